// Round 7
// baseline (5919.646 us; speedup 1.0000x reference)
//
#include <hip/hip_runtime.h>
#include <math.h>

#define HID 2048
#define SEQ 2048
#define N3  6144   // 3*HID
#define NBLK 256
#define NREG 8     // replicated exchange regions (contention spread)

// ---------------------------------------------------------------------------
// GEMM: GI = X @ W_ih^T + b_ih   (fp32, classic 128x128x16 LDS tile, 8x8/thread)
// ---------------------------------------------------------------------------
#define BM 128
#define BN 128
#define BK 16

__global__ __launch_bounds__(256)
void gi_gemm_kernel(const float* __restrict__ X, const float* __restrict__ W,
                    const float* __restrict__ bias, float* __restrict__ GI) {
  __shared__ float As[BK][BM + 4];
  __shared__ float Bs[BK][BN + 4];
  const int tid = threadIdx.x;
  const int bm = blockIdx.y * BM;
  const int bn = blockIdx.x * BN;
  const int tx = tid & 15;
  const int ty = tid >> 4;
  const int lr = tid >> 1;
  const int lk = (tid & 1) * 8;

  float acc[8][8];
#pragma unroll
  for (int i = 0; i < 8; ++i)
#pragma unroll
    for (int j = 0; j < 8; ++j) acc[i][j] = 0.f;

  const float* Arow = X + (size_t)(bm + lr) * HID + lk;
  const float* Brow = W + (size_t)(bn + lr) * HID + lk;

  for (int kc = 0; kc < HID; kc += BK) {
    float4 a0 = *(const float4*)(Arow + kc);
    float4 a1 = *(const float4*)(Arow + kc + 4);
    float4 b0 = *(const float4*)(Brow + kc);
    float4 b1 = *(const float4*)(Brow + kc + 4);
    __syncthreads();
    As[lk + 0][lr] = a0.x; As[lk + 1][lr] = a0.y; As[lk + 2][lr] = a0.z; As[lk + 3][lr] = a0.w;
    As[lk + 4][lr] = a1.x; As[lk + 5][lr] = a1.y; As[lk + 6][lr] = a1.z; As[lk + 7][lr] = a1.w;
    Bs[lk + 0][lr] = b0.x; Bs[lk + 1][lr] = b0.y; Bs[lk + 2][lr] = b0.z; Bs[lk + 3][lr] = b0.w;
    Bs[lk + 4][lr] = b1.x; Bs[lk + 5][lr] = b1.y; Bs[lk + 6][lr] = b1.z; Bs[lk + 7][lr] = b1.w;
    __syncthreads();
#pragma unroll
    for (int kk = 0; kk < BK; ++kk) {
      float4 av0 = *(const float4*)&As[kk][ty * 8];
      float4 av1 = *(const float4*)&As[kk][ty * 8 + 4];
      float4 bv0 = *(const float4*)&Bs[kk][tx * 8];
      float4 bv1 = *(const float4*)&Bs[kk][tx * 8 + 4];
      float a[8] = {av0.x, av0.y, av0.z, av0.w, av1.x, av1.y, av1.z, av1.w};
      float b[8] = {bv0.x, bv0.y, bv0.z, bv0.w, bv1.x, bv1.y, bv1.z, bv1.w};
#pragma unroll
      for (int i = 0; i < 8; ++i)
#pragma unroll
        for (int j = 0; j < 8; ++j)
          acc[i][j] = fmaf(a[i], b[j], acc[i][j]);
    }
  }

  const int n0 = bn + tx * 8;
  float bv[8];
#pragma unroll
  for (int j = 0; j < 8; ++j) bv[j] = bias[n0 + j];
#pragma unroll
  for (int i = 0; i < 8; ++i) {
    float4 o0, o1;
    o0.x = acc[i][0] + bv[0]; o0.y = acc[i][1] + bv[1];
    o0.z = acc[i][2] + bv[2]; o0.w = acc[i][3] + bv[3];
    o1.x = acc[i][4] + bv[4]; o1.y = acc[i][5] + bv[5];
    o1.z = acc[i][6] + bv[6]; o1.w = acc[i][7] + bv[7];
    float* Crow = GI + (size_t)(bm + ty * 8 + i) * N3 + n0;
    *(float4*)Crow = o0;
    *(float4*)(Crow + 4) = o1;
  }
}

// ---------------------------------------------------------------------------
// Persistent recurrent kernel == R2-PROVEN skeleton + WAVE-SPECIALIST POLL:
// Only wave 0 polls (full 8KB row, 8x16B loads in ONE asm ending in
// s_waitcnt vmcnt(0) — the proven-safe pattern: outputs are architecturally
// valid at asm exit, so regalloc copies can't read pre-load garbage, the
// R6 failure mode). Wave 0 unpacks (unpk24 == one v_lshlrev) and stages to
// LDS; waves 1-3 go straight to the barrier. Detection jitter becomes
// max-of-1 instead of max-of-4, poll traffic issued by 64 lanes not 256,
// and 3/4 of waves stop burning VALU on spin. Layout: lane l, load j covers
// units j*256+4l..+3 == consumer fragment lc[jb*256+lane*4]. Designated
// out-row written by designated block's wave 0 from its unpacked regs.
// Exchange protocol (NREG=8, tag8|fp24, 2-buffer), pacing EMA, matvec
// (split phases, AGPR weights), stores: UNCHANGED from R2. Numerics
// bitwise-identical to R2 (same fp24 round-trip, same FMA order).
// ---------------------------------------------------------------------------
template <int CTRL, int ROW_MASK>
__device__ __forceinline__ float dpp_add(float x) {
  int y = __builtin_amdgcn_update_dpp(0, __float_as_uint(x), CTRL, ROW_MASK, 0xf, true);
  return x + __uint_as_float(y);
}

__device__ __forceinline__ float wave_sum(float x) {
  x = dpp_add<0x111, 0xf>(x);  // row_shr:1
  x = dpp_add<0x112, 0xf>(x);  // row_shr:2
  x = dpp_add<0x114, 0xf>(x);  // row_shr:4
  x = dpp_add<0x118, 0xf>(x);  // row_shr:8
  x = dpp_add<0x142, 0xa>(x);  // row_bcast:15, rows 1,3
  x = dpp_add<0x143, 0xc>(x);  // row_bcast:31, rows 2,3
  return __uint_as_float(__builtin_amdgcn_readlane(__float_as_uint(x), 63));
}

__device__ __forceinline__ float rlane(float x, int l) {
  return __uint_as_float(__builtin_amdgcn_readlane(__float_as_uint(x), l));
}

__device__ __forceinline__ float sigf(float x) {
  return __builtin_amdgcn_rcpf(1.f + __expf(-x));
}
__device__ __forceinline__ float tanhfast(float x) {
  return 1.f - 2.f * __builtin_amdgcn_rcpf(1.f + __expf(2.f * x));
}

__device__ __forceinline__ float unpk24(unsigned u) {           // low 24 bits -> fp32
  return __uint_as_float((u & 0x00FFFFFFu) << 8);
}

// 8x16B agent-scope loads (full h row for wave 0), ONE wait INSIDE the asm:
// outputs are valid when the asm retires — no compiler-copy hazard.
#define LD_OCT8()                                                    \
  asm volatile(                                                      \
      "global_load_dwordx4 %0, %8, off sc1\n\t"                      \
      "global_load_dwordx4 %1, %8, off offset:1024 sc1\n\t"          \
      "global_load_dwordx4 %2, %8, off offset:2048 sc1\n\t"          \
      "global_load_dwordx4 %3, %8, off offset:3072 sc1\n\t"          \
      "global_load_dwordx4 %4, %9, off sc1\n\t"                      \
      "global_load_dwordx4 %5, %9, off offset:1024 sc1\n\t"          \
      "global_load_dwordx4 %6, %9, off offset:2048 sc1\n\t"          \
      "global_load_dwordx4 %7, %9, off offset:3072 sc1\n\t"          \
      "s_waitcnt vmcnt(0)"                                           \
      : "=&v"(q0), "=&v"(q1), "=&v"(q2), "=&v"(q3),                  \
        "=&v"(q4), "=&v"(q5), "=&v"(q6), "=&v"(q7)                   \
      : "v"(pb0), "v"(pb1)                                           \
      : "memory")

__global__ __launch_bounds__(256, 1)
void gru_recurrent_kernel(const float* __restrict__ Whh,
                          const float* __restrict__ bhh,
                          const float* __restrict__ GI,      // [t1-t0][N3]
                          float* __restrict__ out,
                          unsigned long long* hpk,           // [NREG][2][HID/2]
                          int t0, int t1) {
  __shared__ float lds_h[2][HID];
  const int tid  = threadIdx.x;
  const int lane = tid & 63;
  const int wv   = tid >> 6;
  const int gw   = blockIdx.x * 4 + wv;   // 0..1023 == this wave's pair-slot
  const int i0   = 2 * gw;
  const int reg  = blockIdx.x & (NREG - 1);

  const int rows[6] = {i0, i0 + 1, HID + i0, HID + i0 + 1, 2 * HID + i0, 2 * HID + i0 + 1};

  // Weights pinned in AGPRs: w[r][jb] covers k = jb*256 + lane*4 + {0..3}
  float4 w[6][8];
#pragma unroll
  for (int r = 0; r < 6; ++r) {
    const float* wr = Whh + (size_t)rows[r] * HID + lane * 4;
#pragma unroll
    for (int jb = 0; jb < 8; ++jb) {
      w[r][jb] = *(const float4*)(wr + jb * 256);
      asm volatile("" : "+a"(w[r][jb].x), "+a"(w[r][jb].y),
                        "+a"(w[r][jb].z), "+a"(w[r][jb].w));
    }
  }

  // wave-uniform biases for the wave's two units
  float br0, br1, bz0, bz1, bn0, bn1;
  {
    float a = 0.f, b = 0.f, c = 0.f;
    if (lane < 2) {
      a = bhh[i0 + lane];
      b = bhh[HID + i0 + lane];
      c = bhh[2 * HID + i0 + lane];
    }
    br0 = rlane(a, 0); br1 = rlane(a, 1);
    bz0 = rlane(b, 0); bz1 = rlane(b, 1);
    bn0 = rlane(c, 0); bn1 = rlane(c, 1);
  }

  // GI prefetch for first step
  float gr = 0.f, gz = 0.f, gn = 0.f;
  if (lane < 2) {
    gr = GI[i0 + lane];
    gz = GI[HID + i0 + lane];
    gn = GI[2 * HID + i0 + lane];
  }

  // rhythm pacing state (wave 0 only; scalar, wave-uniform in practice)
  long long d_prev = 0;     // detect timestamp of previous step
  long long period = 0;     // EMA of inter-step period (cycles)
  const long long MARGIN = 1500;

  for (int t = t0; t < t1; ++t) {
    // ---- issue NEXT step's GI loads FIRST (latency hides under poll/wait) ----
    float pr = 0.f, pz = 0.f, pn = 0.f;
    if (t + 1 < t1 && lane < 2) {
      const float* g = GI + (size_t)(t + 1 - t0) * N3;
      pr = g[i0 + lane];
      pz = g[HID + i0 + lane];
      pn = g[2 * HID + i0 + lane];
    }
    asm volatile("" ::: "memory");   // keep GI loads issued before poll loads

    float* lc = lds_h[t & 1];

    if (wv == 0) {
      // ---- pace: scalar-clock spin until just before expected arrival ----
      if (period > 0) {
        const long long target = d_prev + period - MARGIN;
        while ((long long)__builtin_amdgcn_s_memtime() < target)
          __builtin_amdgcn_s_sleep(1);
      }

      // ---- full-row poll: lane l, load j covers units j*256 + 4l..+3 ----
      const unsigned long long* hb = hpk + ((size_t)reg * 2 + (t & 1)) * (HID / 2);
      const char* pb0 = (const char*)hb + lane * 16;
      const char* pb1 = pb0 + 4096;
      const unsigned tb = (unsigned)t & 0xFFu;
      uint4 q0, q1, q2, q3, q4, q5, q6, q7;
      LD_OCT8();
      for (;;) {
        unsigned bad = 0;
        bad |= ((q0.y >> 24) ^ tb) | ((q0.w >> 24) ^ tb);
        bad |= ((q1.y >> 24) ^ tb) | ((q1.w >> 24) ^ tb);
        bad |= ((q2.y >> 24) ^ tb) | ((q2.w >> 24) ^ tb);
        bad |= ((q3.y >> 24) ^ tb) | ((q3.w >> 24) ^ tb);
        bad |= ((q4.y >> 24) ^ tb) | ((q4.w >> 24) ^ tb);
        bad |= ((q5.y >> 24) ^ tb) | ((q5.w >> 24) ^ tb);
        bad |= ((q6.y >> 24) ^ tb) | ((q6.w >> 24) ^ tb);
        bad |= ((q7.y >> 24) ^ tb) | ((q7.w >> 24) ^ tb);
        if (!bad) break;
        LD_OCT8();
      }

      // ---- update pacing EMA with this step's detect time ----
      {
        const long long now = (long long)__builtin_amdgcn_s_memtime();
        if (d_prev > 0) {
          const long long iv = now - d_prev;
          period = (period > 0) ? period + ((iv - period) >> 3) : iv;
          if (period > 20000) period = 20000;
          if (period < 0) period = 0;
        }
        d_prev = now;
      }

      // ---- unpack + stage to LDS (and out-row for the designated block) ----
      const bool desig = (t > 0) && ((t & (NBLK - 1)) == blockIdx.x);
      float* orow = out + (size_t)(t - 1) * HID;
      float4 f;
#define STAGE1(Q, J)                                                  \
      f.x = unpk24(Q.x); f.y = unpk24(Q.y);                           \
      f.z = unpk24(Q.z); f.w = unpk24(Q.w);                           \
      *(float4*)&lc[(J) * 256 + lane * 4] = f;                        \
      if (desig) *(float4*)(orow + (J) * 256 + lane * 4) = f;
      STAGE1(q0, 0) STAGE1(q1, 1) STAGE1(q2, 2) STAGE1(q3, 3)
      STAGE1(q4, 4) STAGE1(q5, 5) STAGE1(q6, 6) STAGE1(q7, 7)
#undef STAGE1
    }
    __syncthreads();

    // ---- h_prev reads hoisted: hide ds_read latency under the matvec ----
    const float hp0 = lc[i0], hp1 = lc[i0 + 1];

    // ---- matvec phase A: r/z rows (acc0..3); hv kept in registers ----
    float4 hv[8];
    float acc0 = 0.f, acc1 = 0.f, acc2 = 0.f, acc3 = 0.f;
#pragma unroll
    for (int jb = 0; jb < 8; ++jb) {
      hv[jb] = *(const float4*)&lc[jb * 256 + lane * 4];
      acc0 = fmaf(w[0][jb].x, hv[jb].x, acc0); acc0 = fmaf(w[0][jb].y, hv[jb].y, acc0);
      acc0 = fmaf(w[0][jb].z, hv[jb].z, acc0); acc0 = fmaf(w[0][jb].w, hv[jb].w, acc0);
      acc1 = fmaf(w[1][jb].x, hv[jb].x, acc1); acc1 = fmaf(w[1][jb].y, hv[jb].y, acc1);
      acc1 = fmaf(w[1][jb].z, hv[jb].z, acc1); acc1 = fmaf(w[1][jb].w, hv[jb].w, acc1);
      acc2 = fmaf(w[2][jb].x, hv[jb].x, acc2); acc2 = fmaf(w[2][jb].y, hv[jb].y, acc2);
      acc2 = fmaf(w[2][jb].z, hv[jb].z, acc2); acc2 = fmaf(w[2][jb].w, hv[jb].w, acc2);
      acc3 = fmaf(w[3][jb].x, hv[jb].x, acc3); acc3 = fmaf(w[3][jb].y, hv[jb].y, acc3);
      acc3 = fmaf(w[3][jb].z, hv[jb].z, acc3); acc3 = fmaf(w[3][jb].w, hv[jb].w, acc3);
    }

    // ---- reduce+sigmoid of r/z overlaps phase-B FMA stream (scheduler) ----
    const float sr0 = wave_sum(acc0), sr1 = wave_sum(acc1);
    const float sz0 = wave_sum(acc2), sz1 = wave_sum(acc3);

    const float gr0 = rlane(gr, 0), gr1 = rlane(gr, 1);
    const float gz0 = rlane(gz, 0), gz1 = rlane(gz, 1);
    const float gn0 = rlane(gn, 0), gn1 = rlane(gn, 1);

    const float r0 = sigf(gr0 + sr0 + br0);
    const float r1 = sigf(gr1 + sr1 + br1);
    const float z0 = sigf(gz0 + sz0 + bz0);
    const float z1 = sigf(gz1 + sz1 + bz1);

    // ---- matvec phase B: n rows (acc4..5) from registered hv ----
    float acc4 = 0.f, acc5 = 0.f;
#pragma unroll
    for (int jb = 0; jb < 8; ++jb) {
      acc4 = fmaf(w[4][jb].x, hv[jb].x, acc4); acc4 = fmaf(w[4][jb].y, hv[jb].y, acc4);
      acc4 = fmaf(w[4][jb].z, hv[jb].z, acc4); acc4 = fmaf(w[4][jb].w, hv[jb].w, acc4);
      acc5 = fmaf(w[5][jb].x, hv[jb].x, acc5); acc5 = fmaf(w[5][jb].y, hv[jb].y, acc5);
      acc5 = fmaf(w[5][jb].z, hv[jb].z, acc5); acc5 = fmaf(w[5][jb].w, hv[jb].w, acc5);
    }
    const float sn0 = wave_sum(acc4), sn1 = wave_sum(acc5);

    const float n0 = tanhfast(gn0 + r0 * (sn0 + bn0));
    const float n1 = tanhfast(gn1 + r1 * (sn1 + bn1));
    const float hn0 = (1.f - z0) * n0 + z0 * hp0;   // wave-uniform
    const float hn1 = (1.f - z1) * n1 + z1 * hp1;   // wave-uniform

    // ---- pack (tag8|fp24)x2 and store to 8 regions with ONE instruction ----
    {
      const unsigned nt = ((unsigned)(t + 1) & 0xFFu) << 24;
      const unsigned u0 = (__float_as_uint(hn0) + 0x80u) >> 8;   // round-half-up
      const unsigned u1 = (__float_as_uint(hn1) + 0x80u) >> 8;
      const unsigned long long pk =
          ((unsigned long long)(nt | (u1 & 0x00FFFFFFu)) << 32) |
          (nt | (u0 & 0x00FFFFFFu));
      if (lane < NREG) {
        __hip_atomic_store(hpk + ((size_t)lane * 2 + ((t + 1) & 1)) * (HID / 2) + gw,
                           pk, __ATOMIC_RELAXED, __HIP_MEMORY_SCOPE_AGENT);
      }
    }

    if (t == SEQ - 1 && lane == 0) {
      float2 hv2; hv2.x = hn0; hv2.y = hn1;
      *(float2*)(out + (size_t)t * HID + i0) = hv2;          // last out row (exact fp32)
      *(float2*)(out + (size_t)SEQ * HID + i0) = hv2;        // final hidden x2
      *(float2*)(out + (size_t)SEQ * HID + HID + i0) = hv2;
    }

    gr = pr; gz = pz; gn = pn;
  }
}

// ---------------------------------------------------------------------------
extern "C" void kernel_launch(void* const* d_in, const int* in_sizes, int n_in,
                              void* d_out, int out_size, void* d_ws, size_t ws_size,
                              hipStream_t stream) {
  const float* x    = (const float*)d_in[0];
  const float* w_ih = (const float*)d_in[1];
  const float* w_hh = (const float*)d_in[2];
  const float* b_ih = (const float*)d_in[3];
  const float* b_hh = (const float*)d_in[4];
  float* out = (float*)d_out;

  const size_t hpk_bytes = (size_t)NREG * 2 * (HID / 2) * 8;   // 128 KB

  int chunk = SEQ;
  while (chunk > 128 &&
         (size_t)chunk * N3 * 4 + hpk_bytes + 256 > ws_size)
    chunk >>= 1;

  const size_t gi_bytes = (size_t)chunk * N3 * 4;
  float* gi = (float*)d_ws;
  unsigned long long* hpk = (unsigned long long*)((char*)d_ws + gi_bytes);

  // h_0 = 0.0f tagged 0 == all-zero bytes; clears all regions
  (void)hipMemsetAsync(hpk, 0, hpk_bytes, stream);

  for (int t0 = 0; t0 < SEQ; t0 += chunk) {
    dim3 ggrid(N3 / BN, chunk / BM);
    gi_gemm_kernel<<<ggrid, 256, 0, stream>>>(x + (size_t)t0 * HID, w_ih, b_ih, gi);
    gru_recurrent_kernel<<<NBLK, 256, 0, stream>>>(w_hh, b_hh, gi, out, hpk,
                                                   t0, t0 + chunk);
  }
}

// Round 8
// 4887.683 us; speedup vs baseline: 1.2111x; 1.2111x over previous
//
#include <hip/hip_runtime.h>
#include <math.h>

#define HID 2048
#define SEQ 2048
#define N3  6144   // 3*HID
#define NBLK 256
#define NREG 8     // replicated exchange regions (contention spread)

// ---------------------------------------------------------------------------
// GEMM: GI = X @ W_ih^T + b_ih   (fp32, classic 128x128x16 LDS tile, 8x8/thread)
// ---------------------------------------------------------------------------
#define BM 128
#define BN 128
#define BK 16

__global__ __launch_bounds__(256)
void gi_gemm_kernel(const float* __restrict__ X, const float* __restrict__ W,
                    const float* __restrict__ bias, float* __restrict__ GI) {
  __shared__ float As[BK][BM + 4];
  __shared__ float Bs[BK][BN + 4];
  const int tid = threadIdx.x;
  const int bm = blockIdx.y * BM;
  const int bn = blockIdx.x * BN;
  const int tx = tid & 15;
  const int ty = tid >> 4;
  const int lr = tid >> 1;
  const int lk = (tid & 1) * 8;

  float acc[8][8];
#pragma unroll
  for (int i = 0; i < 8; ++i)
#pragma unroll
    for (int j = 0; j < 8; ++j) acc[i][j] = 0.f;

  const float* Arow = X + (size_t)(bm + lr) * HID + lk;
  const float* Brow = W + (size_t)(bn + lr) * HID + lk;

  for (int kc = 0; kc < HID; kc += BK) {
    float4 a0 = *(const float4*)(Arow + kc);
    float4 a1 = *(const float4*)(Arow + kc + 4);
    float4 b0 = *(const float4*)(Brow + kc);
    float4 b1 = *(const float4*)(Brow + kc + 4);
    __syncthreads();
    As[lk + 0][lr] = a0.x; As[lk + 1][lr] = a0.y; As[lk + 2][lr] = a0.z; As[lk + 3][lr] = a0.w;
    As[lk + 4][lr] = a1.x; As[lk + 5][lr] = a1.y; As[lk + 6][lr] = a1.z; As[lk + 7][lr] = a1.w;
    Bs[lk + 0][lr] = b0.x; Bs[lk + 1][lr] = b0.y; Bs[lk + 2][lr] = b0.z; Bs[lk + 3][lr] = b0.w;
    Bs[lk + 4][lr] = b1.x; Bs[lk + 5][lr] = b1.y; Bs[lk + 6][lr] = b1.z; Bs[lk + 7][lr] = b1.w;
    __syncthreads();
#pragma unroll
    for (int kk = 0; kk < BK; ++kk) {
      float4 av0 = *(const float4*)&As[kk][ty * 8];
      float4 av1 = *(const float4*)&As[kk][ty * 8 + 4];
      float4 bv0 = *(const float4*)&Bs[kk][tx * 8];
      float4 bv1 = *(const float4*)&Bs[kk][tx * 8 + 4];
      float a[8] = {av0.x, av0.y, av0.z, av0.w, av1.x, av1.y, av1.z, av1.w};
      float b[8] = {bv0.x, bv0.y, bv0.z, bv0.w, bv1.x, bv1.y, bv1.z, bv1.w};
#pragma unroll
      for (int i = 0; i < 8; ++i)
#pragma unroll
        for (int j = 0; j < 8; ++j)
          acc[i][j] = fmaf(a[i], b[j], acc[i][j]);
    }
  }

  const int n0 = bn + tx * 8;
  float bv[8];
#pragma unroll
  for (int j = 0; j < 8; ++j) bv[j] = bias[n0 + j];
#pragma unroll
  for (int i = 0; i < 8; ++i) {
    float4 o0, o1;
    o0.x = acc[i][0] + bv[0]; o0.y = acc[i][1] + bv[1];
    o0.z = acc[i][2] + bv[2]; o0.w = acc[i][3] + bv[3];
    o1.x = acc[i][4] + bv[4]; o1.y = acc[i][5] + bv[5];
    o1.z = acc[i][6] + bv[6]; o1.w = acc[i][7] + bv[7];
    float* Crow = GI + (size_t)(bm + ty * 8 + i) * N3 + n0;
    *(float4*)Crow = o0;
    *(float4*)(Crow + 4) = o1;
  }
}

// ---------------------------------------------------------------------------
// Persistent recurrent kernel — REVERT to the R2-verified optimum (4957 us):
// distributed quad poll (2x16B sc1 loads/thread, wait INSIDE the asm) +
// distributed LDS staging + barrier + split matvec with AGPR-pinned weights
// + rhythm pacing. Session ledger for why this exact structure:
//  - poll line-request halving (R2): neutral -> line contention not limiting
//  - decoupled waves (R3/R4): container death x2 -> abandoned
//  - counted-vmcnt double-poll (R5/R6): inexpressible (regalloc copies can
//    read pre-load garbage; only vmcnt(0)-inside-one-asm is safe)
//  - wave-specialist poll (R7): -20% (serialized 8KB verify+unpack+stage in
//    one wave inside the dependence chain; distributed detect+stage wins)
// Remaining ~4200cy/step of non-VALU time == agent-scope store->IF$->poll
// visibility + detection overshoot: a latency floor, not a counter roofline.
// ---------------------------------------------------------------------------
template <int CTRL, int ROW_MASK>
__device__ __forceinline__ float dpp_add(float x) {
  int y = __builtin_amdgcn_update_dpp(0, __float_as_uint(x), CTRL, ROW_MASK, 0xf, true);
  return x + __uint_as_float(y);
}

__device__ __forceinline__ float wave_sum(float x) {
  x = dpp_add<0x111, 0xf>(x);  // row_shr:1
  x = dpp_add<0x112, 0xf>(x);  // row_shr:2
  x = dpp_add<0x114, 0xf>(x);  // row_shr:4
  x = dpp_add<0x118, 0xf>(x);  // row_shr:8
  x = dpp_add<0x142, 0xa>(x);  // row_bcast:15, rows 1,3
  x = dpp_add<0x143, 0xc>(x);  // row_bcast:31, rows 2,3
  return __uint_as_float(__builtin_amdgcn_readlane(__float_as_uint(x), 63));
}

__device__ __forceinline__ float rlane(float x, int l) {
  return __uint_as_float(__builtin_amdgcn_readlane(__float_as_uint(x), l));
}

__device__ __forceinline__ float sigf(float x) {
  return __builtin_amdgcn_rcpf(1.f + __expf(-x));
}
__device__ __forceinline__ float tanhfast(float x) {
  return 1.f - 2.f * __builtin_amdgcn_rcpf(1.f + __expf(2.f * x));
}

__device__ __forceinline__ float unpk24(unsigned u) {           // low 24 bits -> fp32
  return __uint_as_float((u & 0x00FFFFFFu) << 8);
}

// dual 16B agent-scope loads, one waitcnt INSIDE the asm (outputs valid at
// asm exit -> no compiler-copy hazard; the only safe poll pattern, R6 lesson)
__device__ __forceinline__ void ld_quad2(const unsigned long long* pa,
                                         const unsigned long long* pb,
                                         uint4& qa, uint4& qb) {
  asm volatile("global_load_dwordx4 %0, %2, off sc1\n\t"
               "global_load_dwordx4 %1, %3, off sc1\n\t"
               "s_waitcnt vmcnt(0)"
               : "=&v"(qa), "=&v"(qb)
               : "v"(pa), "v"(pb)
               : "memory");
}

__global__ __launch_bounds__(256, 1)
void gru_recurrent_kernel(const float* __restrict__ Whh,
                          const float* __restrict__ bhh,
                          const float* __restrict__ GI,      // [t1-t0][N3]
                          float* __restrict__ out,
                          unsigned long long* hpk,           // [NREG][2][HID/2]
                          int t0, int t1) {
  __shared__ float lds_h[2][HID];
  const int tid  = threadIdx.x;
  const int lane = tid & 63;
  const int wv   = tid >> 6;
  const int gw   = blockIdx.x * 4 + wv;   // 0..1023 == this wave's pair-slot
  const int i0   = 2 * gw;
  const int reg  = blockIdx.x & (NREG - 1);

  const int rows[6] = {i0, i0 + 1, HID + i0, HID + i0 + 1, 2 * HID + i0, 2 * HID + i0 + 1};

  // Weights pinned in AGPRs: w[r][jb] covers k = jb*256 + lane*4 + {0..3}
  float4 w[6][8];
#pragma unroll
  for (int r = 0; r < 6; ++r) {
    const float* wr = Whh + (size_t)rows[r] * HID + lane * 4;
#pragma unroll
    for (int jb = 0; jb < 8; ++jb) {
      w[r][jb] = *(const float4*)(wr + jb * 256);
      asm volatile("" : "+a"(w[r][jb].x), "+a"(w[r][jb].y),
                        "+a"(w[r][jb].z), "+a"(w[r][jb].w));
    }
  }

  // wave-uniform biases for the wave's two units
  float br0, br1, bz0, bz1, bn0, bn1;
  {
    float a = 0.f, b = 0.f, c = 0.f;
    if (lane < 2) {
      a = bhh[i0 + lane];
      b = bhh[HID + i0 + lane];
      c = bhh[2 * HID + i0 + lane];
    }
    br0 = rlane(a, 0); br1 = rlane(a, 1);
    bz0 = rlane(b, 0); bz1 = rlane(b, 1);
    bn0 = rlane(c, 0); bn1 = rlane(c, 1);
  }

  // GI prefetch for first step
  float gr = 0.f, gz = 0.f, gn = 0.f;
  if (lane < 2) {
    gr = GI[i0 + lane];
    gz = GI[HID + i0 + lane];
    gn = GI[2 * HID + i0 + lane];
  }

  const int s0 = tid * 2;   // this thread's first pair-slot in each half

  // rhythm pacing state (scalar, wave-uniform in practice)
  long long d_prev = 0;     // detect timestamp of previous step
  long long period = 0;     // EMA of inter-step period (cycles)
  const long long MARGIN = 1500;

  for (int t = t0; t < t1; ++t) {
    // ---- pace: scalar-clock spin until just before expected data arrival ----
    if (period > 0) {
      const long long target = d_prev + period - MARGIN;
      while ((long long)__builtin_amdgcn_s_memtime() < target)
        __builtin_amdgcn_s_sleep(1);
    }

    // ---- issue NEXT step's GI loads FIRST (poll's vmcnt wait covers them) ----
    float pr = 0.f, pz = 0.f, pn = 0.f;
    if (t + 1 < t1 && lane < 2) {
      const float* g = GI + (size_t)(t + 1 - t0) * N3;
      pr = g[i0 + lane];
      pz = g[HID + i0 + lane];
      pn = g[2 * HID + i0 + lane];
    }
    asm volatile("" ::: "memory");   // keep GI loads issued before poll loads

    // ---- quad poll: 2x16B sc1 loads cover 4 pair-slots (8 units)/thread ----
    const unsigned long long* hb = hpk + ((size_t)reg * 2 + (t & 1)) * (HID / 2);
    const unsigned long long* pa = hb + s0;
    const unsigned long long* pb = hb + 512 + s0;
    const unsigned tb = (unsigned)t & 0xFFu;
    uint4 qa, qb;
    ld_quad2(pa, pb, qa, qb);
    for (;;) {
      const bool ok = ((qa.x >> 24) == tb) & ((qa.y >> 24) == tb) &
                      ((qa.z >> 24) == tb) & ((qa.w >> 24) == tb) &
                      ((qb.x >> 24) == tb) & ((qb.y >> 24) == tb) &
                      ((qb.z >> 24) == tb) & ((qb.w >> 24) == tb);
      if (ok) break;
      ld_quad2(pa, pb, qa, qb);
    }

    // ---- update pacing EMA with this step's detect time ----
    {
      const long long now = (long long)__builtin_amdgcn_s_memtime();
      if (d_prev > 0) {
        const long long iv = now - d_prev;
        period = (period > 0) ? period + ((iv - period) >> 3) : iv;
        if (period > 20000) period = 20000;
        if (period < 0) period = 0;
      }
      d_prev = now;
    }

    float* lc = lds_h[t & 1];
    float4 v0, v1;
    v0.x = unpk24(qa.x); v0.y = unpk24(qa.y);
    v0.z = unpk24(qa.z); v0.w = unpk24(qa.w);
    v1.x = unpk24(qb.x); v1.y = unpk24(qb.y);
    v1.z = unpk24(qb.z); v1.w = unpk24(qb.w);
    *(float4*)&lc[tid * 4] = v0;
    *(float4*)&lc[1024 + tid * 4] = v1;
    __syncthreads();

    // ---- h_prev reads hoisted: hide ds_read latency under the matvec ----
    const float hp0 = lc[i0], hp1 = lc[i0 + 1];

    // ---- matvec phase A: r/z rows (acc0..3); hv kept in registers ----
    float4 hv[8];
    float acc0 = 0.f, acc1 = 0.f, acc2 = 0.f, acc3 = 0.f;
#pragma unroll
    for (int jb = 0; jb < 8; ++jb) {
      hv[jb] = *(const float4*)&lc[jb * 256 + lane * 4];
      acc0 = fmaf(w[0][jb].x, hv[jb].x, acc0); acc0 = fmaf(w[0][jb].y, hv[jb].y, acc0);
      acc0 = fmaf(w[0][jb].z, hv[jb].z, acc0); acc0 = fmaf(w[0][jb].w, hv[jb].w, acc0);
      acc1 = fmaf(w[1][jb].x, hv[jb].x, acc1); acc1 = fmaf(w[1][jb].y, hv[jb].y, acc1);
      acc1 = fmaf(w[1][jb].z, hv[jb].z, acc1); acc1 = fmaf(w[1][jb].w, hv[jb].w, acc1);
      acc2 = fmaf(w[2][jb].x, hv[jb].x, acc2); acc2 = fmaf(w[2][jb].y, hv[jb].y, acc2);
      acc2 = fmaf(w[2][jb].z, hv[jb].z, acc2); acc2 = fmaf(w[2][jb].w, hv[jb].w, acc2);
      acc3 = fmaf(w[3][jb].x, hv[jb].x, acc3); acc3 = fmaf(w[3][jb].y, hv[jb].y, acc3);
      acc3 = fmaf(w[3][jb].z, hv[jb].z, acc3); acc3 = fmaf(w[3][jb].w, hv[jb].w, acc3);
    }

    // ---- reduce+sigmoid of r/z overlaps phase-B FMA stream (scheduler) ----
    const float sr0 = wave_sum(acc0), sr1 = wave_sum(acc1);
    const float sz0 = wave_sum(acc2), sz1 = wave_sum(acc3);

    const float gr0 = rlane(gr, 0), gr1 = rlane(gr, 1);
    const float gz0 = rlane(gz, 0), gz1 = rlane(gz, 1);
    const float gn0 = rlane(gn, 0), gn1 = rlane(gn, 1);

    const float r0 = sigf(gr0 + sr0 + br0);
    const float r1 = sigf(gr1 + sr1 + br1);
    const float z0 = sigf(gz0 + sz0 + bz0);
    const float z1 = sigf(gz1 + sz1 + bz1);

    // ---- matvec phase B: n rows (acc4..5) from registered hv ----
    float acc4 = 0.f, acc5 = 0.f;
#pragma unroll
    for (int jb = 0; jb < 8; ++jb) {
      acc4 = fmaf(w[4][jb].x, hv[jb].x, acc4); acc4 = fmaf(w[4][jb].y, hv[jb].y, acc4);
      acc4 = fmaf(w[4][jb].z, hv[jb].z, acc4); acc4 = fmaf(w[4][jb].w, hv[jb].w, acc4);
      acc5 = fmaf(w[5][jb].x, hv[jb].x, acc5); acc5 = fmaf(w[5][jb].y, hv[jb].y, acc5);
      acc5 = fmaf(w[5][jb].z, hv[jb].z, acc5); acc5 = fmaf(w[5][jb].w, hv[jb].w, acc5);
    }
    const float sn0 = wave_sum(acc4), sn1 = wave_sum(acc5);

    const float n0 = tanhfast(gn0 + r0 * (sn0 + bn0));
    const float n1 = tanhfast(gn1 + r1 * (sn1 + bn1));
    const float hn0 = (1.f - z0) * n0 + z0 * hp0;   // wave-uniform
    const float hn1 = (1.f - z1) * n1 + z1 * hp1;   // wave-uniform

    // ---- pack (tag8|fp24)x2 and store to 8 regions with ONE instruction ----
    {
      const unsigned nt = ((unsigned)(t + 1) & 0xFFu) << 24;
      const unsigned u0 = (__float_as_uint(hn0) + 0x80u) >> 8;   // round-half-up
      const unsigned u1 = (__float_as_uint(hn1) + 0x80u) >> 8;
      const unsigned long long pk =
          ((unsigned long long)(nt | (u1 & 0x00FFFFFFu)) << 32) |
          (nt | (u0 & 0x00FFFFFFu));
      if (lane < NREG) {
        __hip_atomic_store(hpk + ((size_t)lane * 2 + ((t + 1) & 1)) * (HID / 2) + gw,
                           pk, __ATOMIC_RELAXED, __HIP_MEMORY_SCOPE_AGENT);
      }
    }

    // designated block writes out row t-1 (== staged h_t, fp24) coalesced
    if (t > 0 && (t & (NBLK - 1)) == blockIdx.x) {
      float* orow = out + (size_t)(t - 1) * HID;
      *(float4*)(orow + tid * 4) = v0;
      *(float4*)(orow + 1024 + tid * 4) = v1;
    }

    if (t == SEQ - 1 && lane == 0) {
      float2 hv2; hv2.x = hn0; hv2.y = hn1;
      *(float2*)(out + (size_t)t * HID + i0) = hv2;          // last out row (exact fp32)
      *(float2*)(out + (size_t)SEQ * HID + i0) = hv2;        // final hidden x2
      *(float2*)(out + (size_t)SEQ * HID + HID + i0) = hv2;
    }

    gr = pr; gz = pz; gn = pn;
  }
}

// ---------------------------------------------------------------------------
extern "C" void kernel_launch(void* const* d_in, const int* in_sizes, int n_in,
                              void* d_out, int out_size, void* d_ws, size_t ws_size,
                              hipStream_t stream) {
  const float* x    = (const float*)d_in[0];
  const float* w_ih = (const float*)d_in[1];
  const float* w_hh = (const float*)d_in[2];
  const float* b_ih = (const float*)d_in[3];
  const float* b_hh = (const float*)d_in[4];
  float* out = (float*)d_out;

  const size_t hpk_bytes = (size_t)NREG * 2 * (HID / 2) * 8;   // 128 KB

  int chunk = SEQ;
  while (chunk > 128 &&
         (size_t)chunk * N3 * 4 + hpk_bytes + 256 > ws_size)
    chunk >>= 1;

  const size_t gi_bytes = (size_t)chunk * N3 * 4;
  float* gi = (float*)d_ws;
  unsigned long long* hpk = (unsigned long long*)((char*)d_ws + gi_bytes);

  // h_0 = 0.0f tagged 0 == all-zero bytes; clears all regions
  (void)hipMemsetAsync(hpk, 0, hpk_bytes, stream);

  for (int t0 = 0; t0 < SEQ; t0 += chunk) {
    dim3 ggrid(N3 / BN, chunk / BM);
    gi_gemm_kernel<<<ggrid, 256, 0, stream>>>(x + (size_t)t0 * HID, w_ih, b_ih, gi);
    gru_recurrent_kernel<<<NBLK, 256, 0, stream>>>(w_hh, b_hh, gi, out, hpk,
                                                   t0, t0 + chunk);
  }
}

// Round 9
// 4852.731 us; speedup vs baseline: 1.2199x; 1.0072x over previous
//
#include <hip/hip_runtime.h>
#include <math.h>

#define HID 2048
#define SEQ 2048
#define N3  6144   // 3*HID
#define NBLK 256
#define NREG 8     // replicated exchange regions (contention spread)

typedef short bhalf8 __attribute__((ext_vector_type(8)));   // 8 bf16 (4 VGPRs)
typedef float f32x4v __attribute__((ext_vector_type(4)));   // MFMA acc

// ---------------------------------------------------------------------------
// Fallback GEMM (fp32, classic 128x128x16 LDS tile, 8x8/thread) — used only
// if workspace can't hold the bf16 split operands.
// ---------------------------------------------------------------------------
#define BM 128
#define BN 128
#define BK 16

__global__ __launch_bounds__(256)
void gi_gemm_kernel(const float* __restrict__ X, const float* __restrict__ W,
                    const float* __restrict__ bias, float* __restrict__ GI) {
  __shared__ float As[BK][BM + 4];
  __shared__ float Bs[BK][BN + 4];
  const int tid = threadIdx.x;
  const int bm = blockIdx.y * BM;
  const int bn = blockIdx.x * BN;
  const int tx = tid & 15;
  const int ty = tid >> 4;
  const int lr = tid >> 1;
  const int lk = (tid & 1) * 8;

  float acc[8][8];
#pragma unroll
  for (int i = 0; i < 8; ++i)
#pragma unroll
    for (int j = 0; j < 8; ++j) acc[i][j] = 0.f;

  const float* Arow = X + (size_t)(bm + lr) * HID + lk;
  const float* Brow = W + (size_t)(bn + lr) * HID + lk;

  for (int kc = 0; kc < HID; kc += BK) {
    float4 a0 = *(const float4*)(Arow + kc);
    float4 a1 = *(const float4*)(Arow + kc + 4);
    float4 b0 = *(const float4*)(Brow + kc);
    float4 b1 = *(const float4*)(Brow + kc + 4);
    __syncthreads();
    As[lk + 0][lr] = a0.x; As[lk + 1][lr] = a0.y; As[lk + 2][lr] = a0.z; As[lk + 3][lr] = a0.w;
    As[lk + 4][lr] = a1.x; As[lk + 5][lr] = a1.y; As[lk + 6][lr] = a1.z; As[lk + 7][lr] = a1.w;
    Bs[lk + 0][lr] = b0.x; Bs[lk + 1][lr] = b0.y; Bs[lk + 2][lr] = b0.z; Bs[lk + 3][lr] = b0.w;
    Bs[lk + 4][lr] = b1.x; Bs[lk + 5][lr] = b1.y; Bs[lk + 6][lr] = b1.z; Bs[lk + 7][lr] = b1.w;
    __syncthreads();
#pragma unroll
    for (int kk = 0; kk < BK; ++kk) {
      float4 av0 = *(const float4*)&As[kk][ty * 8];
      float4 av1 = *(const float4*)&As[kk][ty * 8 + 4];
      float4 bv0 = *(const float4*)&Bs[kk][tx * 8];
      float4 bv1 = *(const float4*)&Bs[kk][tx * 8 + 4];
      float a[8] = {av0.x, av0.y, av0.z, av0.w, av1.x, av1.y, av1.z, av1.w};
      float b[8] = {bv0.x, bv0.y, bv0.z, bv0.w, bv1.x, bv1.y, bv1.z, bv1.w};
#pragma unroll
      for (int i = 0; i < 8; ++i)
#pragma unroll
        for (int j = 0; j < 8; ++j)
          acc[i][j] = fmaf(a[i], b[j], acc[i][j]);
    }
  }

  const int n0 = bn + tx * 8;
  float bv[8];
#pragma unroll
  for (int j = 0; j < 8; ++j) bv[j] = bias[n0 + j];
#pragma unroll
  for (int i = 0; i < 8; ++i) {
    float4 o0, o1;
    o0.x = acc[i][0] + bv[0]; o0.y = acc[i][1] + bv[1];
    o0.z = acc[i][2] + bv[2]; o0.w = acc[i][3] + bv[3];
    o1.x = acc[i][4] + bv[4]; o1.y = acc[i][5] + bv[5];
    o1.z = acc[i][6] + bv[6]; o1.w = acc[i][7] + bv[7];
    float* Crow = GI + (size_t)(bm + ty * 8 + i) * N3 + n0;
    *(float4*)Crow = o0;
    *(float4*)(Crow + 4) = o1;
  }
}

// ---------------------------------------------------------------------------
// NEW: split-bf16 MFMA path for GI = X @ W_ih^T + b.
// fp32 GEMM is vector-ALU-bound (floor 328us, measured ~400). CDNA4 has no
// fp32 MFMA; split each operand into bf16 hi+lo (round-to-nearest) and use
// GI ~= Xhi*Whi + Xhi*Wlo + Xlo*Whi  (lo*lo dropped; rel err ~3*2^-16,
// ~1e-5 absolute -> invisible vs fp24-exchange's 0.0039 absmax).
// 154.6 GFLOP-equiv at 2075 TF 16x16x32 ceiling = 75us floor.
// Fragment layouts (guide-verified family): A: row=lane&15, k=(lane>>4)*8+j;
// B: col=lane&15, same k (contiguous 16B runs of row-major bf16);
// C/D: col=lane&15, row=(lane>>4)*4+reg  [m89-verified].
// ---------------------------------------------------------------------------
__global__ __launch_bounds__(256)
void split_bf16_kernel(const float* __restrict__ src,
                       unsigned short* __restrict__ hi,
                       unsigned short* __restrict__ lo, int n4) {
  const int i = blockIdx.x * 256 + threadIdx.x;
  if (i >= n4) return;
  float4 v = *(const float4*)(src + (size_t)i * 4);
  ushort4 h, l;
#define SP(c, hc, lc)                                                \
  {                                                                  \
    unsigned u = __float_as_uint(v.c);                               \
    unsigned hb = (u + 0x7FFFu + ((u >> 16) & 1u)) >> 16;            \
    float lf = v.c - __uint_as_float(hb << 16);                      \
    unsigned ul = __float_as_uint(lf);                               \
    unsigned lb = (ul + 0x7FFFu + ((ul >> 16) & 1u)) >> 16;          \
    hc = (unsigned short)hb; lc = (unsigned short)lb;                \
  }
  SP(x, h.x, l.x) SP(y, h.y, l.y) SP(z, h.z, l.z) SP(w, h.w, l.w)
#undef SP
  *(ushort4*)(hi + (size_t)i * 4) = h;
  *(ushort4*)(lo + (size_t)i * 4) = l;
}

// block = 4 waves (2m x 2n); wave computes 32x64 (2 m-tiles x 4 n-tiles of
// 16x16); block tile 64x128. Register fragments straight from global (no
// LDS); L1/L3 absorb the A/B reuse (X 16.8MB, W 50MB both L3-resident).
__global__ __launch_bounds__(256)
void gi_gemm_mfma(const unsigned short* __restrict__ Xhi,
                  const unsigned short* __restrict__ Xlo,
                  const unsigned short* __restrict__ Whi,
                  const unsigned short* __restrict__ Wlo,
                  const float* __restrict__ bias, float* __restrict__ GI) {
  const int lane = threadIdx.x & 63;
  const int wv   = threadIdx.x >> 6;
  const int wm = wv >> 1, wn = wv & 1;
  const int m0 = blockIdx.y * 64 + wm * 32;
  const int n0 = blockIdx.x * 128 + wn * 64;
  const int lr = lane & 15;
  const int lk = (lane >> 4) * 8;

  f32x4v acc[2][4];
#pragma unroll
  for (int i = 0; i < 2; ++i)
#pragma unroll
    for (int j = 0; j < 4; ++j) {
      f32x4v z = {0.f, 0.f, 0.f, 0.f};
      acc[i][j] = z;
    }

  const unsigned short* xh = Xhi + (size_t)(m0 + lr) * HID + lk;
  const unsigned short* xl = Xlo + (size_t)(m0 + lr) * HID + lk;
  const unsigned short* wh = Whi + (size_t)(n0 + lr) * HID + lk;
  const unsigned short* wl = Wlo + (size_t)(n0 + lr) * HID + lk;

  for (int k0 = 0; k0 < HID; k0 += 32) {
    bhalf8 ah0 = *(const bhalf8*)(xh + k0);
    bhalf8 ah1 = *(const bhalf8*)(xh + (size_t)16 * HID + k0);
    bhalf8 al0 = *(const bhalf8*)(xl + k0);
    bhalf8 al1 = *(const bhalf8*)(xl + (size_t)16 * HID + k0);
    bhalf8 bh[4], bl[4];
#pragma unroll
    for (int j = 0; j < 4; ++j) {
      bh[j] = *(const bhalf8*)(wh + (size_t)j * 16 * HID + k0);
      bl[j] = *(const bhalf8*)(wl + (size_t)j * 16 * HID + k0);
    }
#pragma unroll
    for (int j = 0; j < 4; ++j) {
      acc[0][j] = __builtin_amdgcn_mfma_f32_16x16x32_bf16(ah0, bh[j], acc[0][j], 0, 0, 0);
      acc[0][j] = __builtin_amdgcn_mfma_f32_16x16x32_bf16(ah0, bl[j], acc[0][j], 0, 0, 0);
      acc[0][j] = __builtin_amdgcn_mfma_f32_16x16x32_bf16(al0, bh[j], acc[0][j], 0, 0, 0);
      acc[1][j] = __builtin_amdgcn_mfma_f32_16x16x32_bf16(ah1, bh[j], acc[1][j], 0, 0, 0);
      acc[1][j] = __builtin_amdgcn_mfma_f32_16x16x32_bf16(ah1, bl[j], acc[1][j], 0, 0, 0);
      acc[1][j] = __builtin_amdgcn_mfma_f32_16x16x32_bf16(al1, bh[j], acc[1][j], 0, 0, 0);
    }
  }

  const int r0 = (lane >> 4) * 4;   // C/D: row=(lane>>4)*4+reg, col=lane&15
#pragma unroll
  for (int j = 0; j < 4; ++j) {
    const int col = n0 + j * 16 + lr;
    const float bv = bias[col];
#pragma unroll
    for (int mi = 0; mi < 2; ++mi) {
#pragma unroll
      for (int r = 0; r < 4; ++r) {
        GI[(size_t)(m0 + mi * 16 + r0 + r) * N3 + col] = acc[mi][j][r] + bv;
      }
    }
  }
}

// ---------------------------------------------------------------------------
// Persistent recurrent kernel — R2/R8-verified optimum (4887us), BYTE-
// IDENTICAL this round: distributed quad poll (2x16B sc1 loads/thread, wait
// INSIDE the asm), distributed LDS staging + barrier, split matvec with
// AGPR-pinned weights, rhythm pacing. Period is a communication-latency
// floor (5 structural attacks: neutral/fatal/inexpressible/-20%).
// ---------------------------------------------------------------------------
template <int CTRL, int ROW_MASK>
__device__ __forceinline__ float dpp_add(float x) {
  int y = __builtin_amdgcn_update_dpp(0, __float_as_uint(x), CTRL, ROW_MASK, 0xf, true);
  return x + __uint_as_float(y);
}

__device__ __forceinline__ float wave_sum(float x) {
  x = dpp_add<0x111, 0xf>(x);  // row_shr:1
  x = dpp_add<0x112, 0xf>(x);  // row_shr:2
  x = dpp_add<0x114, 0xf>(x);  // row_shr:4
  x = dpp_add<0x118, 0xf>(x);  // row_shr:8
  x = dpp_add<0x142, 0xa>(x);  // row_bcast:15, rows 1,3
  x = dpp_add<0x143, 0xc>(x);  // row_bcast:31, rows 2,3
  return __uint_as_float(__builtin_amdgcn_readlane(__float_as_uint(x), 63));
}

__device__ __forceinline__ float rlane(float x, int l) {
  return __uint_as_float(__builtin_amdgcn_readlane(__float_as_uint(x), l));
}

__device__ __forceinline__ float sigf(float x) {
  return __builtin_amdgcn_rcpf(1.f + __expf(-x));
}
__device__ __forceinline__ float tanhfast(float x) {
  return 1.f - 2.f * __builtin_amdgcn_rcpf(1.f + __expf(2.f * x));
}

__device__ __forceinline__ float unpk24(unsigned u) {           // low 24 bits -> fp32
  return __uint_as_float((u & 0x00FFFFFFu) << 8);
}

// dual 16B agent-scope loads, one waitcnt INSIDE the asm (outputs valid at
// asm exit -> no compiler-copy hazard; the only safe poll pattern, R6 lesson)
__device__ __forceinline__ void ld_quad2(const unsigned long long* pa,
                                         const unsigned long long* pb,
                                         uint4& qa, uint4& qb) {
  asm volatile("global_load_dwordx4 %0, %2, off sc1\n\t"
               "global_load_dwordx4 %1, %3, off sc1\n\t"
               "s_waitcnt vmcnt(0)"
               : "=&v"(qa), "=&v"(qb)
               : "v"(pa), "v"(pb)
               : "memory");
}

__global__ __launch_bounds__(256, 1)
void gru_recurrent_kernel(const float* __restrict__ Whh,
                          const float* __restrict__ bhh,
                          const float* __restrict__ GI,      // [t1-t0][N3]
                          float* __restrict__ out,
                          unsigned long long* hpk,           // [NREG][2][HID/2]
                          int t0, int t1) {
  __shared__ float lds_h[2][HID];
  const int tid  = threadIdx.x;
  const int lane = tid & 63;
  const int wv   = tid >> 6;
  const int gw   = blockIdx.x * 4 + wv;   // 0..1023 == this wave's pair-slot
  const int i0   = 2 * gw;
  const int reg  = blockIdx.x & (NREG - 1);

  const int rows[6] = {i0, i0 + 1, HID + i0, HID + i0 + 1, 2 * HID + i0, 2 * HID + i0 + 1};

  // Weights pinned in AGPRs: w[r][jb] covers k = jb*256 + lane*4 + {0..3}
  float4 w[6][8];
#pragma unroll
  for (int r = 0; r < 6; ++r) {
    const float* wr = Whh + (size_t)rows[r] * HID + lane * 4;
#pragma unroll
    for (int jb = 0; jb < 8; ++jb) {
      w[r][jb] = *(const float4*)(wr + jb * 256);
      asm volatile("" : "+a"(w[r][jb].x), "+a"(w[r][jb].y),
                        "+a"(w[r][jb].z), "+a"(w[r][jb].w));
    }
  }

  // wave-uniform biases for the wave's two units
  float br0, br1, bz0, bz1, bn0, bn1;
  {
    float a = 0.f, b = 0.f, c = 0.f;
    if (lane < 2) {
      a = bhh[i0 + lane];
      b = bhh[HID + i0 + lane];
      c = bhh[2 * HID + i0 + lane];
    }
    br0 = rlane(a, 0); br1 = rlane(a, 1);
    bz0 = rlane(b, 0); bz1 = rlane(b, 1);
    bn0 = rlane(c, 0); bn1 = rlane(c, 1);
  }

  // GI prefetch for first step
  float gr = 0.f, gz = 0.f, gn = 0.f;
  if (lane < 2) {
    gr = GI[i0 + lane];
    gz = GI[HID + i0 + lane];
    gn = GI[2 * HID + i0 + lane];
  }

  const int s0 = tid * 2;   // this thread's first pair-slot in each half

  // rhythm pacing state (scalar, wave-uniform in practice)
  long long d_prev = 0;     // detect timestamp of previous step
  long long period = 0;     // EMA of inter-step period (cycles)
  const long long MARGIN = 1500;

  for (int t = t0; t < t1; ++t) {
    // ---- pace: scalar-clock spin until just before expected data arrival ----
    if (period > 0) {
      const long long target = d_prev + period - MARGIN;
      while ((long long)__builtin_amdgcn_s_memtime() < target)
        __builtin_amdgcn_s_sleep(1);
    }

    // ---- issue NEXT step's GI loads FIRST (poll's vmcnt wait covers them) ----
    float pr = 0.f, pz = 0.f, pn = 0.f;
    if (t + 1 < t1 && lane < 2) {
      const float* g = GI + (size_t)(t + 1 - t0) * N3;
      pr = g[i0 + lane];
      pz = g[HID + i0 + lane];
      pn = g[2 * HID + i0 + lane];
    }
    asm volatile("" ::: "memory");   // keep GI loads issued before poll loads

    // ---- quad poll: 2x16B sc1 loads cover 4 pair-slots (8 units)/thread ----
    const unsigned long long* hb = hpk + ((size_t)reg * 2 + (t & 1)) * (HID / 2);
    const unsigned long long* pa = hb + s0;
    const unsigned long long* pb = hb + 512 + s0;
    const unsigned tb = (unsigned)t & 0xFFu;
    uint4 qa, qb;
    ld_quad2(pa, pb, qa, qb);
    for (;;) {
      const bool ok = ((qa.x >> 24) == tb) & ((qa.y >> 24) == tb) &
                      ((qa.z >> 24) == tb) & ((qa.w >> 24) == tb) &
                      ((qb.x >> 24) == tb) & ((qb.y >> 24) == tb) &
                      ((qb.z >> 24) == tb) & ((qb.w >> 24) == tb);
      if (ok) break;
      ld_quad2(pa, pb, qa, qb);
    }

    // ---- update pacing EMA with this step's detect time ----
    {
      const long long now = (long long)__builtin_amdgcn_s_memtime();
      if (d_prev > 0) {
        const long long iv = now - d_prev;
        period = (period > 0) ? period + ((iv - period) >> 3) : iv;
        if (period > 20000) period = 20000;
        if (period < 0) period = 0;
      }
      d_prev = now;
    }

    float* lc = lds_h[t & 1];
    float4 v0, v1;
    v0.x = unpk24(qa.x); v0.y = unpk24(qa.y);
    v0.z = unpk24(qa.z); v0.w = unpk24(qa.w);
    v1.x = unpk24(qb.x); v1.y = unpk24(qb.y);
    v1.z = unpk24(qb.z); v1.w = unpk24(qb.w);
    *(float4*)&lc[tid * 4] = v0;
    *(float4*)&lc[1024 + tid * 4] = v1;
    __syncthreads();

    // ---- h_prev reads hoisted: hide ds_read latency under the matvec ----
    const float hp0 = lc[i0], hp1 = lc[i0 + 1];

    // ---- matvec phase A: r/z rows (acc0..3); hv kept in registers ----
    float4 hv[8];
    float acc0 = 0.f, acc1 = 0.f, acc2 = 0.f, acc3 = 0.f;
#pragma unroll
    for (int jb = 0; jb < 8; ++jb) {
      hv[jb] = *(const float4*)&lc[jb * 256 + lane * 4];
      acc0 = fmaf(w[0][jb].x, hv[jb].x, acc0); acc0 = fmaf(w[0][jb].y, hv[jb].y, acc0);
      acc0 = fmaf(w[0][jb].z, hv[jb].z, acc0); acc0 = fmaf(w[0][jb].w, hv[jb].w, acc0);
      acc1 = fmaf(w[1][jb].x, hv[jb].x, acc1); acc1 = fmaf(w[1][jb].y, hv[jb].y, acc1);
      acc1 = fmaf(w[1][jb].z, hv[jb].z, acc1); acc1 = fmaf(w[1][jb].w, hv[jb].w, acc1);
      acc2 = fmaf(w[2][jb].x, hv[jb].x, acc2); acc2 = fmaf(w[2][jb].y, hv[jb].y, acc2);
      acc2 = fmaf(w[2][jb].z, hv[jb].z, acc2); acc2 = fmaf(w[2][jb].w, hv[jb].w, acc2);
      acc3 = fmaf(w[3][jb].x, hv[jb].x, acc3); acc3 = fmaf(w[3][jb].y, hv[jb].y, acc3);
      acc3 = fmaf(w[3][jb].z, hv[jb].z, acc3); acc3 = fmaf(w[3][jb].w, hv[jb].w, acc3);
    }

    // ---- reduce+sigmoid of r/z overlaps phase-B FMA stream (scheduler) ----
    const float sr0 = wave_sum(acc0), sr1 = wave_sum(acc1);
    const float sz0 = wave_sum(acc2), sz1 = wave_sum(acc3);

    const float gr0 = rlane(gr, 0), gr1 = rlane(gr, 1);
    const float gz0 = rlane(gz, 0), gz1 = rlane(gz, 1);
    const float gn0 = rlane(gn, 0), gn1 = rlane(gn, 1);

    const float r0 = sigf(gr0 + sr0 + br0);
    const float r1 = sigf(gr1 + sr1 + br1);
    const float z0 = sigf(gz0 + sz0 + bz0);
    const float z1 = sigf(gz1 + sz1 + bz1);

    // ---- matvec phase B: n rows (acc4..5) from registered hv ----
    float acc4 = 0.f, acc5 = 0.f;
#pragma unroll
    for (int jb = 0; jb < 8; ++jb) {
      acc4 = fmaf(w[4][jb].x, hv[jb].x, acc4); acc4 = fmaf(w[4][jb].y, hv[jb].y, acc4);
      acc4 = fmaf(w[4][jb].z, hv[jb].z, acc4); acc4 = fmaf(w[4][jb].w, hv[jb].w, acc4);
      acc5 = fmaf(w[5][jb].x, hv[jb].x, acc5); acc5 = fmaf(w[5][jb].y, hv[jb].y, acc5);
      acc5 = fmaf(w[5][jb].z, hv[jb].z, acc5); acc5 = fmaf(w[5][jb].w, hv[jb].w, acc5);
    }
    const float sn0 = wave_sum(acc4), sn1 = wave_sum(acc5);

    const float n0 = tanhfast(gn0 + r0 * (sn0 + bn0));
    const float n1 = tanhfast(gn1 + r1 * (sn1 + bn1));
    const float hn0 = (1.f - z0) * n0 + z0 * hp0;   // wave-uniform
    const float hn1 = (1.f - z1) * n1 + z1 * hp1;   // wave-uniform

    // ---- pack (tag8|fp24)x2 and store to 8 regions with ONE instruction ----
    {
      const unsigned nt = ((unsigned)(t + 1) & 0xFFu) << 24;
      const unsigned u0 = (__float_as_uint(hn0) + 0x80u) >> 8;   // round-half-up
      const unsigned u1 = (__float_as_uint(hn1) + 0x80u) >> 8;
      const unsigned long long pk =
          ((unsigned long long)(nt | (u1 & 0x00FFFFFFu)) << 32) |
          (nt | (u0 & 0x00FFFFFFu));
      if (lane < NREG) {
        __hip_atomic_store(hpk + ((size_t)lane * 2 + ((t + 1) & 1)) * (HID / 2) + gw,
                           pk, __ATOMIC_RELAXED, __HIP_MEMORY_SCOPE_AGENT);
      }
    }

    // designated block writes out row t-1 (== staged h_t, fp24) coalesced
    if (t > 0 && (t & (NBLK - 1)) == blockIdx.x) {
      float* orow = out + (size_t)(t - 1) * HID;
      *(float4*)(orow + tid * 4) = v0;
      *(float4*)(orow + 1024 + tid * 4) = v1;
    }

    if (t == SEQ - 1 && lane == 0) {
      float2 hv2; hv2.x = hn0; hv2.y = hn1;
      *(float2*)(out + (size_t)t * HID + i0) = hv2;          // last out row (exact fp32)
      *(float2*)(out + (size_t)SEQ * HID + i0) = hv2;        // final hidden x2
      *(float2*)(out + (size_t)SEQ * HID + HID + i0) = hv2;
    }

    gr = pr; gz = pz; gn = pn;
  }
}

// ---------------------------------------------------------------------------
extern "C" void kernel_launch(void* const* d_in, const int* in_sizes, int n_in,
                              void* d_out, int out_size, void* d_ws, size_t ws_size,
                              hipStream_t stream) {
  const float* x    = (const float*)d_in[0];
  const float* w_ih = (const float*)d_in[1];
  const float* w_hh = (const float*)d_in[2];
  const float* b_ih = (const float*)d_in[3];
  const float* b_hh = (const float*)d_in[4];
  float* out = (float*)d_out;

  const size_t hpk_bytes = (size_t)NREG * 2 * (HID / 2) * 8;        // 128 KB
  const size_t xs  = (size_t)SEQ * HID * sizeof(unsigned short);    // 8.4 MB per half
  const size_t wsp = (size_t)N3 * HID * sizeof(unsigned short);     // 25.2 MB per half

  // ---- try MFMA path: GI + hpk + Xhi/Xlo + Whi/Wlo must fit in ws ----
  int chunk = SEQ;
  while (chunk > 128 &&
         (size_t)chunk * N3 * 4 + hpk_bytes + 2 * xs + 2 * wsp + 1024 > ws_size)
    chunk >>= 1;
  const bool use_mfma =
      ((size_t)chunk * N3 * 4 + hpk_bytes + 2 * xs + 2 * wsp + 1024 <= ws_size);

  if (use_mfma) {
    char* p = (char*)d_ws;
    float* gi = (float*)p;                    p += (size_t)chunk * N3 * 4;
    unsigned long long* hpk = (unsigned long long*)p;  p += hpk_bytes;
    unsigned short* Xhi = (unsigned short*)p; p += xs;
    unsigned short* Xlo = (unsigned short*)p; p += xs;
    unsigned short* Whi = (unsigned short*)p; p += wsp;
    unsigned short* Wlo = (unsigned short*)p;

    (void)hipMemsetAsync(hpk, 0, hpk_bytes, stream);
    split_bf16_kernel<<<(SEQ * HID / 4 + 255) / 256, 256, 0, stream>>>(
        x, Xhi, Xlo, SEQ * HID / 4);
    split_bf16_kernel<<<(N3 * HID / 4 + 255) / 256, 256, 0, stream>>>(
        w_ih, Whi, Wlo, N3 * HID / 4);

    for (int t0 = 0; t0 < SEQ; t0 += chunk) {
      dim3 g(N3 / 128, chunk / 64);
      gi_gemm_mfma<<<g, 256, 0, stream>>>(Xhi + (size_t)t0 * HID,
                                          Xlo + (size_t)t0 * HID,
                                          Whi, Wlo, b_ih, gi);
      gru_recurrent_kernel<<<NBLK, 256, 0, stream>>>(w_hh, b_hh, gi, out, hpk,
                                                     t0, t0 + chunk);
    }
  } else {
    // ---- fallback: R8-proven fp32 GEMM path, unchanged ----
    int fchunk = SEQ;
    while (fchunk > 128 &&
           (size_t)fchunk * N3 * 4 + hpk_bytes + 256 > ws_size)
      fchunk >>= 1;

    const size_t gi_bytes = (size_t)fchunk * N3 * 4;
    float* gi = (float*)d_ws;
    unsigned long long* hpk = (unsigned long long*)((char*)d_ws + gi_bytes);

    (void)hipMemsetAsync(hpk, 0, hpk_bytes, stream);

    for (int t0 = 0; t0 < SEQ; t0 += fchunk) {
      dim3 ggrid(N3 / BN, fchunk / BM);
      gi_gemm_kernel<<<ggrid, 256, 0, stream>>>(x + (size_t)t0 * HID, w_ih, b_ih, gi);
      gru_recurrent_kernel<<<NBLK, 256, 0, stream>>>(w_hh, b_hh, gi, out, hpk,
                                                     t0, t0 + fchunk);
    }
  }
}

// Round 10
// 4742.333 us; speedup vs baseline: 1.2483x; 1.0233x over previous
//
#include <hip/hip_runtime.h>
#include <math.h>

#define HID 2048
#define SEQ 2048
#define N3  6144   // 3*HID
#define NBLK 256
#define NREG 8     // replicated exchange regions (contention spread)

typedef short bhalf8 __attribute__((ext_vector_type(8)));   // 8 bf16 (4 VGPRs)
typedef float f32x4v __attribute__((ext_vector_type(4)));   // MFMA acc

// ---------------------------------------------------------------------------
// Fallback GEMM (fp32, classic 128x128x16 LDS tile, 8x8/thread) — used only
// if workspace can't hold the bf16 split operands.
// ---------------------------------------------------------------------------
#define BM 128
#define BN 128
#define BK 16

__global__ __launch_bounds__(256)
void gi_gemm_kernel(const float* __restrict__ X, const float* __restrict__ W,
                    const float* __restrict__ bias, float* __restrict__ GI) {
  __shared__ float As[BK][BM + 4];
  __shared__ float Bs[BK][BN + 4];
  const int tid = threadIdx.x;
  const int bm = blockIdx.y * BM;
  const int bn = blockIdx.x * BN;
  const int tx = tid & 15;
  const int ty = tid >> 4;
  const int lr = tid >> 1;
  const int lk = (tid & 1) * 8;

  float acc[8][8];
#pragma unroll
  for (int i = 0; i < 8; ++i)
#pragma unroll
    for (int j = 0; j < 8; ++j) acc[i][j] = 0.f;

  const float* Arow = X + (size_t)(bm + lr) * HID + lk;
  const float* Brow = W + (size_t)(bn + lr) * HID + lk;

  for (int kc = 0; kc < HID; kc += BK) {
    float4 a0 = *(const float4*)(Arow + kc);
    float4 a1 = *(const float4*)(Arow + kc + 4);
    float4 b0 = *(const float4*)(Brow + kc);
    float4 b1 = *(const float4*)(Brow + kc + 4);
    __syncthreads();
    As[lk + 0][lr] = a0.x; As[lk + 1][lr] = a0.y; As[lk + 2][lr] = a0.z; As[lk + 3][lr] = a0.w;
    As[lk + 4][lr] = a1.x; As[lk + 5][lr] = a1.y; As[lk + 6][lr] = a1.z; As[lk + 7][lr] = a1.w;
    Bs[lk + 0][lr] = b0.x; Bs[lk + 1][lr] = b0.y; Bs[lk + 2][lr] = b0.z; Bs[lk + 3][lr] = b0.w;
    Bs[lk + 4][lr] = b1.x; Bs[lk + 5][lr] = b1.y; Bs[lk + 6][lr] = b1.z; Bs[lk + 7][lr] = b1.w;
    __syncthreads();
#pragma unroll
    for (int kk = 0; kk < BK; ++kk) {
      float4 av0 = *(const float4*)&As[kk][ty * 8];
      float4 av1 = *(const float4*)&As[kk][ty * 8 + 4];
      float4 bv0 = *(const float4*)&Bs[kk][tx * 8];
      float4 bv1 = *(const float4*)&Bs[kk][tx * 8 + 4];
      float a[8] = {av0.x, av0.y, av0.z, av0.w, av1.x, av1.y, av1.z, av1.w};
      float b[8] = {bv0.x, bv0.y, bv0.z, bv0.w, bv1.x, bv1.y, bv1.z, bv1.w};
#pragma unroll
      for (int i = 0; i < 8; ++i)
#pragma unroll
        for (int j = 0; j < 8; ++j)
          acc[i][j] = fmaf(a[i], b[j], acc[i][j]);
    }
  }

  const int n0 = bn + tx * 8;
  float bv[8];
#pragma unroll
  for (int j = 0; j < 8; ++j) bv[j] = bias[n0 + j];
#pragma unroll
  for (int i = 0; i < 8; ++i) {
    float4 o0, o1;
    o0.x = acc[i][0] + bv[0]; o0.y = acc[i][1] + bv[1];
    o0.z = acc[i][2] + bv[2]; o0.w = acc[i][3] + bv[3];
    o1.x = acc[i][4] + bv[4]; o1.y = acc[i][5] + bv[5];
    o1.z = acc[i][6] + bv[6]; o1.w = acc[i][7] + bv[7];
    float* Crow = GI + (size_t)(bm + ty * 8 + i) * N3 + n0;
    *(float4*)Crow = o0;
    *(float4*)(Crow + 4) = o1;
  }
}

// ---------------------------------------------------------------------------
// split-bf16 MFMA path for GI = X @ W_ih^T + b (R9-verified, absmax clean).
// GI ~= Xhi*Whi + Xhi*Wlo + Xlo*Whi (lo*lo dropped; ~1e-5 abs, invisible vs
// fp24-exchange 0.0039). R10 changes (GEMM only):
//  (1) 64x64 wave tiles (block 128x128): 16 loads -> 48 MFMA per K-iter,
//      1.5x better load:MFMA ratio than R9's 12:24.
//  (2) T1 chunked XCD swizzle (nwg always %8==0): each XCD owns a contiguous
//      run of original block ids -> A-stripes no longer replicated into all
//      8 per-XCD L2s; stride-48 B-stripe reusers stay XCD-local.
// ---------------------------------------------------------------------------
__global__ __launch_bounds__(256)
void split_bf16_kernel(const float* __restrict__ src,
                       unsigned short* __restrict__ hi,
                       unsigned short* __restrict__ lo, int n4) {
  const int i = blockIdx.x * 256 + threadIdx.x;
  if (i >= n4) return;
  float4 v = *(const float4*)(src + (size_t)i * 4);
  ushort4 h, l;
#define SP(c, hc, lc)                                                \
  {                                                                  \
    unsigned u = __float_as_uint(v.c);                               \
    unsigned hb = (u + 0x7FFFu + ((u >> 16) & 1u)) >> 16;            \
    float lf = v.c - __uint_as_float(hb << 16);                      \
    unsigned ul = __float_as_uint(lf);                               \
    unsigned lb = (ul + 0x7FFFu + ((ul >> 16) & 1u)) >> 16;          \
    hc = (unsigned short)hb; lc = (unsigned short)lb;                \
  }
  SP(x, h.x, l.x) SP(y, h.y, l.y) SP(z, h.z, l.z) SP(w, h.w, l.w)
#undef SP
  *(ushort4*)(hi + (size_t)i * 4) = h;
  *(ushort4*)(lo + (size_t)i * 4) = l;
}

// block = 4 waves (2m x 2n); wave computes 64x64 (4x4 16x16 tiles); block
// tile 128x128. Register fragments straight from global (L1/L2/L3 absorb
// reuse). Fragment layouts: A/B row=lane&15, k=(lane>>4)*8+j (contiguous
// 16B of row-major bf16); C/D col=lane&15, row=(lane>>4)*4+reg.
__global__ __launch_bounds__(256)
void gi_gemm_mfma(const unsigned short* __restrict__ Xhi,
                  const unsigned short* __restrict__ Xlo,
                  const unsigned short* __restrict__ Whi,
                  const unsigned short* __restrict__ Wlo,
                  const float* __restrict__ bias, float* __restrict__ GI) {
  // T1 chunked XCD swizzle (perf-only permutation; nwg % 8 == 0 always:
  // nwg = 48 * (chunk/128), 48 % 8 == 0)
  const int nwg = gridDim.x * gridDim.y;
  const int hw  = blockIdx.y * gridDim.x + blockIdx.x;
  const int cpx = nwg >> 3;
  const int orig = (hw & 7) * cpx + (hw >> 3);
  const int bx = orig % gridDim.x;
  const int by = orig / gridDim.x;

  const int lane = threadIdx.x & 63;
  const int wv   = threadIdx.x >> 6;
  const int wm = wv >> 1, wn = wv & 1;
  const int m0 = by * 128 + wm * 64;
  const int n0 = bx * 128 + wn * 64;
  const int lr = lane & 15;
  const int lk = (lane >> 4) * 8;

  f32x4v acc[4][4];
#pragma unroll
  for (int i = 0; i < 4; ++i)
#pragma unroll
    for (int j = 0; j < 4; ++j) {
      f32x4v z = {0.f, 0.f, 0.f, 0.f};
      acc[i][j] = z;
    }

  const unsigned short* xh = Xhi + (size_t)(m0 + lr) * HID + lk;
  const unsigned short* xl = Xlo + (size_t)(m0 + lr) * HID + lk;
  const unsigned short* wh = Whi + (size_t)(n0 + lr) * HID + lk;
  const unsigned short* wl = Wlo + (size_t)(n0 + lr) * HID + lk;

  for (int k0 = 0; k0 < HID; k0 += 32) {
    bhalf8 ah[4], al[4], bh[4], bl[4];
#pragma unroll
    for (int mi = 0; mi < 4; ++mi) {
      ah[mi] = *(const bhalf8*)(xh + (size_t)mi * 16 * HID + k0);
      al[mi] = *(const bhalf8*)(xl + (size_t)mi * 16 * HID + k0);
    }
#pragma unroll
    for (int nj = 0; nj < 4; ++nj) {
      bh[nj] = *(const bhalf8*)(wh + (size_t)nj * 16 * HID + k0);
      bl[nj] = *(const bhalf8*)(wl + (size_t)nj * 16 * HID + k0);
    }
#pragma unroll
    for (int mi = 0; mi < 4; ++mi) {
#pragma unroll
      for (int nj = 0; nj < 4; ++nj) {
        acc[mi][nj] = __builtin_amdgcn_mfma_f32_16x16x32_bf16(ah[mi], bh[nj], acc[mi][nj], 0, 0, 0);
        acc[mi][nj] = __builtin_amdgcn_mfma_f32_16x16x32_bf16(ah[mi], bl[nj], acc[mi][nj], 0, 0, 0);
        acc[mi][nj] = __builtin_amdgcn_mfma_f32_16x16x32_bf16(al[mi], bh[nj], acc[mi][nj], 0, 0, 0);
      }
    }
  }

  const int r0 = (lane >> 4) * 4;   // C/D: row=(lane>>4)*4+reg, col=lane&15
#pragma unroll
  for (int nj = 0; nj < 4; ++nj) {
    const int col = n0 + nj * 16 + lr;
    const float bv = bias[col];
#pragma unroll
    for (int mi = 0; mi < 4; ++mi) {
#pragma unroll
      for (int r = 0; r < 4; ++r) {
        GI[(size_t)(m0 + mi * 16 + r0 + r) * N3 + col] = acc[mi][nj][r] + bv;
      }
    }
  }
}

// ---------------------------------------------------------------------------
// Persistent recurrent kernel — R2/R8/R9-verified optimum, BYTE-IDENTICAL:
// distributed quad poll (2x16B sc1 loads/thread, wait INSIDE the asm),
// distributed LDS staging + barrier, split matvec with AGPR-pinned weights,
// rhythm pacing. Period is a communication-latency floor (5 structural
// attacks: neutral / fatal / inexpressible / -20% / tuned).
// ---------------------------------------------------------------------------
template <int CTRL, int ROW_MASK>
__device__ __forceinline__ float dpp_add(float x) {
  int y = __builtin_amdgcn_update_dpp(0, __float_as_uint(x), CTRL, ROW_MASK, 0xf, true);
  return x + __uint_as_float(y);
}

__device__ __forceinline__ float wave_sum(float x) {
  x = dpp_add<0x111, 0xf>(x);  // row_shr:1
  x = dpp_add<0x112, 0xf>(x);  // row_shr:2
  x = dpp_add<0x114, 0xf>(x);  // row_shr:4
  x = dpp_add<0x118, 0xf>(x);  // row_shr:8
  x = dpp_add<0x142, 0xa>(x);  // row_bcast:15, rows 1,3
  x = dpp_add<0x143, 0xc>(x);  // row_bcast:31, rows 2,3
  return __uint_as_float(__builtin_amdgcn_readlane(__float_as_uint(x), 63));
}

__device__ __forceinline__ float rlane(float x, int l) {
  return __uint_as_float(__builtin_amdgcn_readlane(__float_as_uint(x), l));
}

__device__ __forceinline__ float sigf(float x) {
  return __builtin_amdgcn_rcpf(1.f + __expf(-x));
}
__device__ __forceinline__ float tanhfast(float x) {
  return 1.f - 2.f * __builtin_amdgcn_rcpf(1.f + __expf(2.f * x));
}

__device__ __forceinline__ float unpk24(unsigned u) {           // low 24 bits -> fp32
  return __uint_as_float((u & 0x00FFFFFFu) << 8);
}

// dual 16B agent-scope loads, one waitcnt INSIDE the asm (outputs valid at
// asm exit -> no compiler-copy hazard; the only safe poll pattern, R6 lesson)
__device__ __forceinline__ void ld_quad2(const unsigned long long* pa,
                                         const unsigned long long* pb,
                                         uint4& qa, uint4& qb) {
  asm volatile("global_load_dwordx4 %0, %2, off sc1\n\t"
               "global_load_dwordx4 %1, %3, off sc1\n\t"
               "s_waitcnt vmcnt(0)"
               : "=&v"(qa), "=&v"(qb)
               : "v"(pa), "v"(pb)
               : "memory");
}

__global__ __launch_bounds__(256, 1)
void gru_recurrent_kernel(const float* __restrict__ Whh,
                          const float* __restrict__ bhh,
                          const float* __restrict__ GI,      // [t1-t0][N3]
                          float* __restrict__ out,
                          unsigned long long* hpk,           // [NREG][2][HID/2]
                          int t0, int t1) {
  __shared__ float lds_h[2][HID];
  const int tid  = threadIdx.x;
  const int lane = tid & 63;
  const int wv   = tid >> 6;
  const int gw   = blockIdx.x * 4 + wv;   // 0..1023 == this wave's pair-slot
  const int i0   = 2 * gw;
  const int reg  = blockIdx.x & (NREG - 1);

  const int rows[6] = {i0, i0 + 1, HID + i0, HID + i0 + 1, 2 * HID + i0, 2 * HID + i0 + 1};

  // Weights pinned in AGPRs: w[r][jb] covers k = jb*256 + lane*4 + {0..3}
  float4 w[6][8];
#pragma unroll
  for (int r = 0; r < 6; ++r) {
    const float* wr = Whh + (size_t)rows[r] * HID + lane * 4;
#pragma unroll
    for (int jb = 0; jb < 8; ++jb) {
      w[r][jb] = *(const float4*)(wr + jb * 256);
      asm volatile("" : "+a"(w[r][jb].x), "+a"(w[r][jb].y),
                        "+a"(w[r][jb].z), "+a"(w[r][jb].w));
    }
  }

  // wave-uniform biases for the wave's two units
  float br0, br1, bz0, bz1, bn0, bn1;
  {
    float a = 0.f, b = 0.f, c = 0.f;
    if (lane < 2) {
      a = bhh[i0 + lane];
      b = bhh[HID + i0 + lane];
      c = bhh[2 * HID + i0 + lane];
    }
    br0 = rlane(a, 0); br1 = rlane(a, 1);
    bz0 = rlane(b, 0); bz1 = rlane(b, 1);
    bn0 = rlane(c, 0); bn1 = rlane(c, 1);
  }

  // GI prefetch for first step
  float gr = 0.f, gz = 0.f, gn = 0.f;
  if (lane < 2) {
    gr = GI[i0 + lane];
    gz = GI[HID + i0 + lane];
    gn = GI[2 * HID + i0 + lane];
  }

  const int s0 = tid * 2;   // this thread's first pair-slot in each half

  // rhythm pacing state (scalar, wave-uniform in practice)
  long long d_prev = 0;     // detect timestamp of previous step
  long long period = 0;     // EMA of inter-step period (cycles)
  const long long MARGIN = 1500;

  for (int t = t0; t < t1; ++t) {
    // ---- pace: scalar-clock spin until just before expected data arrival ----
    if (period > 0) {
      const long long target = d_prev + period - MARGIN;
      while ((long long)__builtin_amdgcn_s_memtime() < target)
        __builtin_amdgcn_s_sleep(1);
    }

    // ---- issue NEXT step's GI loads FIRST (poll's vmcnt wait covers them) ----
    float pr = 0.f, pz = 0.f, pn = 0.f;
    if (t + 1 < t1 && lane < 2) {
      const float* g = GI + (size_t)(t + 1 - t0) * N3;
      pr = g[i0 + lane];
      pz = g[HID + i0 + lane];
      pn = g[2 * HID + i0 + lane];
    }
    asm volatile("" ::: "memory");   // keep GI loads issued before poll loads

    // ---- quad poll: 2x16B sc1 loads cover 4 pair-slots (8 units)/thread ----
    const unsigned long long* hb = hpk + ((size_t)reg * 2 + (t & 1)) * (HID / 2);
    const unsigned long long* pa = hb + s0;
    const unsigned long long* pb = hb + 512 + s0;
    const unsigned tb = (unsigned)t & 0xFFu;
    uint4 qa, qb;
    ld_quad2(pa, pb, qa, qb);
    for (;;) {
      const bool ok = ((qa.x >> 24) == tb) & ((qa.y >> 24) == tb) &
                      ((qa.z >> 24) == tb) & ((qa.w >> 24) == tb) &
                      ((qb.x >> 24) == tb) & ((qb.y >> 24) == tb) &
                      ((qb.z >> 24) == tb) & ((qb.w >> 24) == tb);
      if (ok) break;
      ld_quad2(pa, pb, qa, qb);
    }

    // ---- update pacing EMA with this step's detect time ----
    {
      const long long now = (long long)__builtin_amdgcn_s_memtime();
      if (d_prev > 0) {
        const long long iv = now - d_prev;
        period = (period > 0) ? period + ((iv - period) >> 3) : iv;
        if (period > 20000) period = 20000;
        if (period < 0) period = 0;
      }
      d_prev = now;
    }

    float* lc = lds_h[t & 1];
    float4 v0, v1;
    v0.x = unpk24(qa.x); v0.y = unpk24(qa.y);
    v0.z = unpk24(qa.z); v0.w = unpk24(qa.w);
    v1.x = unpk24(qb.x); v1.y = unpk24(qb.y);
    v1.z = unpk24(qb.z); v1.w = unpk24(qb.w);
    *(float4*)&lc[tid * 4] = v0;
    *(float4*)&lc[1024 + tid * 4] = v1;
    __syncthreads();

    // ---- h_prev reads hoisted: hide ds_read latency under the matvec ----
    const float hp0 = lc[i0], hp1 = lc[i0 + 1];

    // ---- matvec phase A: r/z rows (acc0..3); hv kept in registers ----
    float4 hv[8];
    float acc0 = 0.f, acc1 = 0.f, acc2 = 0.f, acc3 = 0.f;
#pragma unroll
    for (int jb = 0; jb < 8; ++jb) {
      hv[jb] = *(const float4*)&lc[jb * 256 + lane * 4];
      acc0 = fmaf(w[0][jb].x, hv[jb].x, acc0); acc0 = fmaf(w[0][jb].y, hv[jb].y, acc0);
      acc0 = fmaf(w[0][jb].z, hv[jb].z, acc0); acc0 = fmaf(w[0][jb].w, hv[jb].w, acc0);
      acc1 = fmaf(w[1][jb].x, hv[jb].x, acc1); acc1 = fmaf(w[1][jb].y, hv[jb].y, acc1);
      acc1 = fmaf(w[1][jb].z, hv[jb].z, acc1); acc1 = fmaf(w[1][jb].w, hv[jb].w, acc1);
      acc2 = fmaf(w[2][jb].x, hv[jb].x, acc2); acc2 = fmaf(w[2][jb].y, hv[jb].y, acc2);
      acc2 = fmaf(w[2][jb].z, hv[jb].z, acc2); acc2 = fmaf(w[2][jb].w, hv[jb].w, acc2);
      acc3 = fmaf(w[3][jb].x, hv[jb].x, acc3); acc3 = fmaf(w[3][jb].y, hv[jb].y, acc3);
      acc3 = fmaf(w[3][jb].z, hv[jb].z, acc3); acc3 = fmaf(w[3][jb].w, hv[jb].w, acc3);
    }

    // ---- reduce+sigmoid of r/z overlaps phase-B FMA stream (scheduler) ----
    const float sr0 = wave_sum(acc0), sr1 = wave_sum(acc1);
    const float sz0 = wave_sum(acc2), sz1 = wave_sum(acc3);

    const float gr0 = rlane(gr, 0), gr1 = rlane(gr, 1);
    const float gz0 = rlane(gz, 0), gz1 = rlane(gz, 1);
    const float gn0 = rlane(gn, 0), gn1 = rlane(gn, 1);

    const float r0 = sigf(gr0 + sr0 + br0);
    const float r1 = sigf(gr1 + sr1 + br1);
    const float z0 = sigf(gz0 + sz0 + bz0);
    const float z1 = sigf(gz1 + sz1 + bz1);

    // ---- matvec phase B: n rows (acc4..5) from registered hv ----
    float acc4 = 0.f, acc5 = 0.f;
#pragma unroll
    for (int jb = 0; jb < 8; ++jb) {
      acc4 = fmaf(w[4][jb].x, hv[jb].x, acc4); acc4 = fmaf(w[4][jb].y, hv[jb].y, acc4);
      acc4 = fmaf(w[4][jb].z, hv[jb].z, acc4); acc4 = fmaf(w[4][jb].w, hv[jb].w, acc4);
      acc5 = fmaf(w[5][jb].x, hv[jb].x, acc5); acc5 = fmaf(w[5][jb].y, hv[jb].y, acc5);
      acc5 = fmaf(w[5][jb].z, hv[jb].z, acc5); acc5 = fmaf(w[5][jb].w, hv[jb].w, acc5);
    }
    const float sn0 = wave_sum(acc4), sn1 = wave_sum(acc5);

    const float n0 = tanhfast(gn0 + r0 * (sn0 + bn0));
    const float n1 = tanhfast(gn1 + r1 * (sn1 + bn1));
    const float hn0 = (1.f - z0) * n0 + z0 * hp0;   // wave-uniform
    const float hn1 = (1.f - z1) * n1 + z1 * hp1;   // wave-uniform

    // ---- pack (tag8|fp24)x2 and store to 8 regions with ONE instruction ----
    {
      const unsigned nt = ((unsigned)(t + 1) & 0xFFu) << 24;
      const unsigned u0 = (__float_as_uint(hn0) + 0x80u) >> 8;   // round-half-up
      const unsigned u1 = (__float_as_uint(hn1) + 0x80u) >> 8;
      const unsigned long long pk =
          ((unsigned long long)(nt | (u1 & 0x00FFFFFFu)) << 32) |
          (nt | (u0 & 0x00FFFFFFu));
      if (lane < NREG) {
        __hip_atomic_store(hpk + ((size_t)lane * 2 + ((t + 1) & 1)) * (HID / 2) + gw,
                           pk, __ATOMIC_RELAXED, __HIP_MEMORY_SCOPE_AGENT);
      }
    }

    // designated block writes out row t-1 (== staged h_t, fp24) coalesced
    if (t > 0 && (t & (NBLK - 1)) == blockIdx.x) {
      float* orow = out + (size_t)(t - 1) * HID;
      *(float4*)(orow + tid * 4) = v0;
      *(float4*)(orow + 1024 + tid * 4) = v1;
    }

    if (t == SEQ - 1 && lane == 0) {
      float2 hv2; hv2.x = hn0; hv2.y = hn1;
      *(float2*)(out + (size_t)t * HID + i0) = hv2;          // last out row (exact fp32)
      *(float2*)(out + (size_t)SEQ * HID + i0) = hv2;        // final hidden x2
      *(float2*)(out + (size_t)SEQ * HID + HID + i0) = hv2;
    }

    gr = pr; gz = pz; gn = pn;
  }
}

// ---------------------------------------------------------------------------
extern "C" void kernel_launch(void* const* d_in, const int* in_sizes, int n_in,
                              void* d_out, int out_size, void* d_ws, size_t ws_size,
                              hipStream_t stream) {
  const float* x    = (const float*)d_in[0];
  const float* w_ih = (const float*)d_in[1];
  const float* w_hh = (const float*)d_in[2];
  const float* b_ih = (const float*)d_in[3];
  const float* b_hh = (const float*)d_in[4];
  float* out = (float*)d_out;

  const size_t hpk_bytes = (size_t)NREG * 2 * (HID / 2) * 8;        // 128 KB
  const size_t xs  = (size_t)SEQ * HID * sizeof(unsigned short);    // 8.4 MB per half
  const size_t wsp = (size_t)N3 * HID * sizeof(unsigned short);     // 25.2 MB per half

  // ---- try MFMA path: GI + hpk + Xhi/Xlo + Whi/Wlo must fit in ws ----
  int chunk = SEQ;
  while (chunk > 128 &&
         (size_t)chunk * N3 * 4 + hpk_bytes + 2 * xs + 2 * wsp + 1024 > ws_size)
    chunk >>= 1;
  const bool use_mfma =
      ((size_t)chunk * N3 * 4 + hpk_bytes + 2 * xs + 2 * wsp + 1024 <= ws_size);

  if (use_mfma) {
    char* p = (char*)d_ws;
    float* gi = (float*)p;                    p += (size_t)chunk * N3 * 4;
    unsigned long long* hpk = (unsigned long long*)p;  p += hpk_bytes;
    unsigned short* Xhi = (unsigned short*)p; p += xs;
    unsigned short* Xlo = (unsigned short*)p; p += xs;
    unsigned short* Whi = (unsigned short*)p; p += wsp;
    unsigned short* Wlo = (unsigned short*)p;

    (void)hipMemsetAsync(hpk, 0, hpk_bytes, stream);
    split_bf16_kernel<<<(SEQ * HID / 4 + 255) / 256, 256, 0, stream>>>(
        x, Xhi, Xlo, SEQ * HID / 4);
    split_bf16_kernel<<<(N3 * HID / 4 + 255) / 256, 256, 0, stream>>>(
        w_ih, Whi, Wlo, N3 * HID / 4);

    for (int t0 = 0; t0 < SEQ; t0 += chunk) {
      dim3 g(N3 / 128, chunk / 128);
      gi_gemm_mfma<<<g, 256, 0, stream>>>(Xhi + (size_t)t0 * HID,
                                          Xlo + (size_t)t0 * HID,
                                          Whi, Wlo, b_ih, gi);
      gru_recurrent_kernel<<<NBLK, 256, 0, stream>>>(w_hh, b_hh, gi, out, hpk,
                                                     t0, t0 + chunk);
    }
  } else {
    // ---- fallback: R8-proven fp32 GEMM path, unchanged ----
    int fchunk = SEQ;
    while (fchunk > 128 &&
           (size_t)fchunk * N3 * 4 + hpk_bytes + 256 > ws_size)
      fchunk >>= 1;

    const size_t gi_bytes = (size_t)fchunk * N3 * 4;
    float* gi = (float*)d_ws;
    unsigned long long* hpk = (unsigned long long*)((char*)d_ws + gi_bytes);

    (void)hipMemsetAsync(hpk, 0, hpk_bytes, stream);

    for (int t0 = 0; t0 < SEQ; t0 += fchunk) {
      dim3 ggrid(N3 / BN, fchunk / BM);
      gi_gemm_kernel<<<ggrid, 256, 0, stream>>>(x + (size_t)t0 * HID, w_ih, b_ih, gi);
      gru_recurrent_kernel<<<NBLK, 256, 0, stream>>>(w_hh, b_hh, gi, out, hpk,
                                                     t0, t0 + fchunk);
    }
  }
}